// Round 1
// baseline (271.383 us; speedup 1.0000x reference)
//
#include <hip/hip_runtime.h>

#define T_N 1024
#define B_N 512
#define HID 20
#define TB3 (T_N * B_N * 3)   // 1572864
#define CHUNK 64

// ---------------- Kernel 1: memory MLP, me[r] = sigmoid(MLP(t_r)) ----------------
__global__ __launch_bounds__(256) void me_mlp_kernel(
    const float* __restrict__ t,
    const float* __restrict__ w1, const float* __restrict__ b1,
    const float* __restrict__ w2, const float* __restrict__ b2,
    const float* __restrict__ w3, const float* __restrict__ b3,
    const float* __restrict__ w4, const float* __restrict__ b4,
    float* __restrict__ me)
{
    const int r = blockIdx.x * 256 + threadIdx.x;
    if (r >= T_N) return;
    const float x = t[r];
    float h1[HID], h2[HID], h3[HID];
    #pragma unroll
    for (int k = 0; k < HID; ++k) h1[k] = tanhf(x * w1[k] + b1[k]);
    for (int j = 0; j < HID; ++j) {
        float s = b2[j];
        #pragma unroll
        for (int k = 0; k < HID; ++k) s += h1[k] * w2[k * HID + j];
        h2[j] = tanhf(s);
    }
    for (int j = 0; j < HID; ++j) {
        float s = b3[j];
        #pragma unroll
        for (int k = 0; k < HID; ++k) s += h2[k] * w3[k * HID + j];
        h3[j] = tanhf(s);
    }
    float o = b4[0];
    #pragma unroll
    for (int k = 0; k < HID; ++k) o += h3[k] * w4[k];
    me[r] = 1.0f / (1.0f + expf(-o));
}

// ---------------- Kernel 2: one wave per body, blocked convolution ----------------
// integro_j = dt * sum_{d=1..j} ker[d] * I[j-d],  ker[d] = me[T-d]
__global__ __launch_bounds__(64, 1) void ode_kernel(
    const float* __restrict__ t,
    const float* __restrict__ y,
    const float* __restrict__ me,
    const float* __restrict__ betap,
    const float* __restrict__ gammap,
    float* __restrict__ out)
{
    const int b    = blockIdx.x;   // body
    const int lane = threadIdx.x;  // 0..63

    __shared__ float kl[T_N];      // kl[d] = me[T-d], d>=1 ; kl[0]=0
    __shared__ float Ih[T_N];      // I history (steps 0..1023)
    __shared__ float Hs[CHUNK];    // per-chunk history dot results

    for (int d = lane; d < T_N; d += 64)
        kl[d] = (d == 0) ? 0.0f : me[T_N - d];

    const float dt  = t[0] - t[1];
    const float bet = betap[0];
    const float gam = gammap[0];

    float S = y[3 * b + 0];
    float I = y[3 * b + 1];
    float R = y[3 * b + 2];

    if (lane == 0) Ih[0] = I;
    if (lane < 3) {
        out[3 * b + lane] = y[3 * b + lane];                       // solution row 0
        out[TB3 + (size_t)1023 * B_N * 3 + 3 * b + lane] = 0.0f;   // diff row 1023
    }
    __syncthreads();

    // lag kernel for within-chunk part, register-resident (wave-uniform)
    float kr[CHUNK];
    #pragma unroll
    for (int d = 1; d < CHUNK; ++d) kr[d] = kl[d];
    kr[0] = 0.0f;

    float Iloc[CHUNK];

    for (int p = 0; p < T_N / CHUNK; ++p) {
        const int Js = p * CHUNK;

        // ---- Phase A (lane-parallel): H[c] = sum_{i<Js} Ih[i] * kl[Js+c-i] ----
        float a0 = 0.f, a1 = 0.f, a2 = 0.f, a3 = 0.f;
        {
            const int base = Js + lane;
            #pragma unroll 2
            for (int i = 0; i < Js; i += 4) {
                const float4 iv = *reinterpret_cast<const float4*>(&Ih[i]);
                a0 += iv.x * kl[base - i];
                a1 += iv.y * kl[base - i - 1];
                a2 += iv.z * kl[base - i - 2];
                a3 += iv.w * kl[base - i - 3];
            }
        }
        Hs[lane] = (a0 + a1) + (a2 + a3);
        __syncthreads();

        // ---- Phase B (serial, redundant on all lanes) ----
        float mdS = 0.f, mdI = 0.f, mdR = 0.f, mS = 0.f, mI = 0.f, mR = 0.f;

        // c = 0
        if (p == 0) {
            Iloc[0] = I;   // j = 0 is the initial condition, not a step
        } else {
            const float integro = Hs[0] * dt;
            const float bSI = bet * S * I;
            const float dS = integro - bSI;
            const float dI = bSI - gam * I;
            const float dR = gam * I - integro;
            S += dS * dt; I += dI * dt; R += dR * dt;
            Iloc[0] = I;
            if (lane == 0) { mdS = dS; mdI = dI; mdR = dR; mS = S; mI = I; mR = R; }
        }

        #pragma unroll
        for (int c = 1; c < CHUNK; ++c) {
            float w0 = 0.f, w1_ = 0.f, w2_ = 0.f, w3_ = 0.f;
            #pragma unroll
            for (int d = 1; d <= c; ++d) {
                const float term = kr[d] * Iloc[c - d];
                switch ((d - 1) & 3) {
                    case 0: w0  += term; break;
                    case 1: w1_ += term; break;
                    case 2: w2_ += term; break;
                    default: w3_ += term; break;
                }
            }
            const float w = (w0 + w1_) + (w2_ + w3_);
            const float integro = (Hs[c] + w) * dt;
            const float bSI = bet * S * I;
            const float dS = integro - bSI;
            const float dI = bSI - gam * I;
            const float dR = gam * I - integro;
            S += dS * dt; I += dI * dt; R += dR * dt;
            Iloc[c] = I;
            if (lane == c) { mdS = dS; mdI = dI; mdR = dR; mS = S; mI = I; mR = R; }
        }
        __syncthreads();   // Phase B's Hs reads done before next chunk overwrites

        // publish this chunk's I values to history + write outputs (one step per lane)
        const int j = Js + lane;
        if (j >= 1) {
            Ih[j] = mI;
            float* so = out + (size_t)j * B_N * 3 + 3 * b;
            so[0] = mS; so[1] = mI; so[2] = mR;
            float* df = out + TB3 + (size_t)(j - 1) * B_N * 3 + 3 * b;
            df[0] = mdS; df[1] = mdI; df[2] = mdR;
        }
        __syncthreads();   // Ih writes visible before next Phase A
    }
}

// ---------------- launcher ----------------
extern "C" void kernel_launch(void* const* d_in, const int* in_sizes, int n_in,
                              void* d_out, int out_size, void* d_ws, size_t ws_size,
                              hipStream_t stream)
{
    const float* t   = (const float*)d_in[0];
    const float* y   = (const float*)d_in[1];
    const float* w1  = (const float*)d_in[2];
    const float* b1  = (const float*)d_in[3];
    const float* w2  = (const float*)d_in[4];
    const float* b2  = (const float*)d_in[5];
    const float* w3  = (const float*)d_in[6];
    const float* b3  = (const float*)d_in[7];
    const float* w4  = (const float*)d_in[8];
    const float* b4  = (const float*)d_in[9];
    const float* bet = (const float*)d_in[10];
    const float* gam = (const float*)d_in[11];
    float* out = (float*)d_out;
    float* me  = (float*)d_ws;   // 1024 floats of scratch

    me_mlp_kernel<<<dim3((T_N + 255) / 256), dim3(256), 0, stream>>>(
        t, w1, b1, w2, b2, w3, b3, w4, b4, me);
    ode_kernel<<<dim3(B_N), dim3(64), 0, stream>>>(t, y, me, bet, gam, out);
}

// Round 2
// 177.270 us; speedup vs baseline: 1.5309x; 1.5309x over previous
//
#include <hip/hip_runtime.h>

#define T_N 1024
#define B_N 512
#define HID 20
#define TB3 (T_N * B_N * 3)   // 1572864

// ---------------- Kernel 1: memory MLP, me[r] = sigmoid(MLP(t_r)) ----------------
__global__ __launch_bounds__(256) void me_mlp_kernel(
    const float* __restrict__ t,
    const float* __restrict__ w1, const float* __restrict__ b1,
    const float* __restrict__ w2, const float* __restrict__ b2,
    const float* __restrict__ w3, const float* __restrict__ b3,
    const float* __restrict__ w4, const float* __restrict__ b4,
    float* __restrict__ me)
{
    const int r = blockIdx.x * 256 + threadIdx.x;
    if (r >= T_N) return;
    const float x = t[r];
    float h1[HID], h2[HID], h3[HID];
    #pragma unroll
    for (int k = 0; k < HID; ++k) h1[k] = tanhf(x * w1[k] + b1[k]);
    for (int j = 0; j < HID; ++j) {
        float s = b2[j];
        #pragma unroll
        for (int k = 0; k < HID; ++k) s += h1[k] * w2[k * HID + j];
        h2[j] = tanhf(s);
    }
    for (int j = 0; j < HID; ++j) {
        float s = b3[j];
        #pragma unroll
        for (int k = 0; k < HID; ++k) s += h2[k] * w3[k * HID + j];
        h3[j] = tanhf(s);
    }
    float o = b4[0];
    #pragma unroll
    for (int k = 0; k < HID; ++k) o += h3[k] * w4[k];
    me[r] = 1.0f / (1.0f + expf(-o));
}

__device__ __forceinline__ float bcast_lane(float v, int lane) {
    return __int_as_float(__builtin_amdgcn_readlane(__float_as_int(v), lane));
}

// ---------------- Kernel 2: 4 waves per body ----------------
// integro_j = dt * sum_{d=1..j} kl[d] * I[j-d],  kl[d] = me[T-d], kl[0] = 0
__global__ __launch_bounds__(256, 2) void ode_kernel(
    const float* __restrict__ t,
    const float* __restrict__ y,
    const float* __restrict__ me,
    const float* __restrict__ betap,
    const float* __restrict__ gammap,
    float* __restrict__ out)
{
    const int b    = blockIdx.x;          // body
    const int tx   = threadIdx.x;
    const int lane = tx & 63;
    const int wv   = tx >> 6;             // wave 0..3

    // kls[s][d] = kl[d+s]; 4 copies shifted by s, rows padded +8 floats so the
    // four copies occupy disjoint bank groups (row stride 1032 -> 8-bank shift).
    __shared__ __align__(16) float kls[4][1032];
    __shared__ __align__(16) float Ih[T_N];   // I history, steps 0..1023
    __shared__ float Hs[4][64];               // per-wave Phase-A partials

    for (int d = tx; d < 1032; d += 256) {
        #pragma unroll
        for (int s = 0; s < 4; ++s) {
            const int e = d + s;
            kls[s][d] = (e >= 1 && e <= 1023) ? me[T_N - e] : 0.0f;
        }
    }

    const float dt  = t[0] - t[1];        // = 1/1024 exactly
    const float rdt = 1.0f / dt;          // exact (power of two)
    const float bet = betap[0];
    const float gam = gammap[0];

    float S = y[3 * b + 0];
    float I = y[3 * b + 1];
    float R = y[3 * b + 2];

    if (tx == 0) Ih[0] = I;
    if (tx < 3) {
        out[3 * b + tx] = y[3 * b + tx];                        // solution row 0
        out[TB3 + (size_t)1023 * B_N * 3 + 3 * b + tx] = 0.0f;  // diff row 1023
    }
    __syncthreads();

    const float* kls0 = &kls[0][0];
    // lane-constant offset for Phase A aligned-b128 reads:
    // element index read = kls[(lane+1)&3][off - i .. off - i + 3] = kl[Js+lane-i-3 .. Js+lane-i]
    const int s_my  = (lane + 1) & 3;
    const int offc  = lane - 3 - s_my;    // in {-4, 0}, ≡ 0 mod 4
    const float4* kr4  = (const float4*)&kls[s_my][0];
    const float4* Ih4  = (const float4*)&Ih[0];

    for (int p = 0; p < 16; ++p) {
        const int Js   = p * 64;
        const int qlen = p * 16;          // per-wave i-range length

        // ---- Phase A (all 4 waves): H[c] = sum_{i<Js} Ih[i] * kl[Js+c-i] ----
        float a0 = 0.f, a1 = 0.f, a2 = 0.f, a3 = 0.f;
        {
            const int i0 = wv * qlen;
            const int i1 = i0 + qlen;
            const int kbase4 = (Js + offc) >> 2;   // (Js+offc)/4, exact
            for (int i = i0; i < i1; i += 8) {
                const float4 iv0 = Ih4[(i >> 2)];
                const float4 iv1 = Ih4[(i >> 2) + 1];
                const float4 k0  = kr4[kbase4 - (i >> 2)];
                const float4 k1  = kr4[kbase4 - (i >> 2) - 1];
                a0 += iv0.x * k0.w; a1 += iv0.y * k0.z;
                a2 += iv0.z * k0.y; a3 += iv0.w * k0.x;
                a0 += iv1.x * k1.w; a1 += iv1.y * k1.z;
                a2 += iv1.z * k1.y; a3 += iv1.w * k1.x;
            }
        }
        Hs[wv][lane] = (a0 + a1) + (a2 + a3);
        __syncthreads();

        // ---- Phase B (wave 0 only): 64 serial steps, O(1) work per step ----
        if (wv == 0) {
            const float hw = Hs[0][lane] + Hs[1][lane] + Hs[2][lane] + Hs[3][lane];
            float W = 0.0f;
            float mS = S, mI = I, mR = R;
            const float cS = S, cI = I, cR = R;   // state at chunk entry (step Js-1)

            // kl-coefficient ring, prefetched 4 steps ahead
            float kv0 = kls0[lane];
            float kv1 = kls0[(lane - 1 > 0) ? lane - 1 : 0];
            float kv2 = kls0[(lane - 2 > 0) ? lane - 2 : 0];
            float kv3 = kls0[(lane - 3 > 0) ? lane - 3 : 0];
            int kidx = lane - 4;

#define STEP(II, KV)                                                      \
            {                                                             \
                const int ii = (II);                                      \
                float updt = (p == 0 && ii == 0) ? 0.0f : dt;             \
                float tot = bcast_lane(hw + W, ii);                       \
                float integro = tot * dt;                                 \
                float bSI = bet * S * I;                                  \
                float dS = integro - bSI;                                 \
                float dI = bSI - gam * I;                                 \
                float dR = -dS - dI;                                      \
                S += dS * updt; I += dI * updt; R += dR * updt;           \
                if (lane == ii) { mS = S; mI = I; mR = R; }               \
                W = fmaf(KV, I, W);                                       \
                KV = kls0[(kidx > 0) ? kidx : 0];                         \
                --kidx;                                                   \
            }

            #pragma unroll 1
            for (int q = 0; q < 16; ++q) {
                const int base = q * 4;
                STEP(base + 0, kv0)
                STEP(base + 1, kv1)
                STEP(base + 2, kv2)
                STEP(base + 3, kv3)
            }
#undef STEP

            // publish history for next chunk's Phase A
            Ih[Js + lane] = mI;

            // outputs: solution row j = (mS,mI,mR); diff row j-1 = (y_j - y_{j-1})/dt
            const int j = Js + lane;
            float pS = __shfl_up(mS, 1);
            float pI = __shfl_up(mI, 1);
            float pR = __shfl_up(mR, 1);
            if (lane == 0) { pS = cS; pI = cI; pR = cR; }
            if (j >= 1) {
                float* so = out + (size_t)j * (B_N * 3) + 3 * b;
                so[0] = mS; so[1] = mI; so[2] = mR;
                float* df = out + TB3 + (size_t)(j - 1) * (B_N * 3) + 3 * b;
                df[0] = (mS - pS) * rdt;
                df[1] = (mI - pI) * rdt;
                df[2] = (mR - pR) * rdt;
            }
            // carry running state (= step Js+63) into next chunk
            // (S,I,R already hold it)
        }
        __syncthreads();
    }
}

// ---------------- launcher ----------------
extern "C" void kernel_launch(void* const* d_in, const int* in_sizes, int n_in,
                              void* d_out, int out_size, void* d_ws, size_t ws_size,
                              hipStream_t stream)
{
    const float* t   = (const float*)d_in[0];
    const float* y   = (const float*)d_in[1];
    const float* w1  = (const float*)d_in[2];
    const float* b1  = (const float*)d_in[3];
    const float* w2  = (const float*)d_in[4];
    const float* b2  = (const float*)d_in[5];
    const float* w3  = (const float*)d_in[6];
    const float* b3  = (const float*)d_in[7];
    const float* w4  = (const float*)d_in[8];
    const float* b4  = (const float*)d_in[9];
    const float* bet = (const float*)d_in[10];
    const float* gam = (const float*)d_in[11];
    float* out = (float*)d_out;
    float* me  = (float*)d_ws;   // 1024 floats of scratch

    me_mlp_kernel<<<dim3((T_N + 255) / 256), dim3(256), 0, stream>>>(
        t, w1, b1, w2, b2, w3, b3, w4, b4, me);
    ode_kernel<<<dim3(B_N), dim3(256), 0, stream>>>(t, y, me, bet, gam, out);
}

// Round 4
// 165.237 us; speedup vs baseline: 1.6424x; 1.0728x over previous
//
#include <hip/hip_runtime.h>

#define T_N 1024
#define B_N 512
#define HID 20
#define TB3 (T_N * B_N * 3)   // 1572864

__device__ __forceinline__ float bcast_lane(float v, int lane) {
    return __int_as_float(__builtin_amdgcn_readlane(__float_as_int(v), lane));
}

// ---------------- Kernel 1: memory MLP (round-2 proven version) ----------------
__global__ __launch_bounds__(256) void me_mlp_kernel(
    const float* __restrict__ t,
    const float* __restrict__ w1, const float* __restrict__ b1,
    const float* __restrict__ w2, const float* __restrict__ b2,
    const float* __restrict__ w3, const float* __restrict__ b3,
    const float* __restrict__ w4, const float* __restrict__ b4,
    float* __restrict__ me)
{
    const int r = blockIdx.x * 256 + threadIdx.x;
    if (r >= T_N) return;
    const float x = t[r];
    float h1[HID], h2[HID], h3[HID];
    #pragma unroll
    for (int k = 0; k < HID; ++k) h1[k] = tanhf(x * w1[k] + b1[k]);
    for (int j = 0; j < HID; ++j) {
        float s = b2[j];
        #pragma unroll
        for (int k = 0; k < HID; ++k) s += h1[k] * w2[k * HID + j];
        h2[j] = tanhf(s);
    }
    for (int j = 0; j < HID; ++j) {
        float s = b3[j];
        #pragma unroll
        for (int k = 0; k < HID; ++k) s += h2[k] * w3[k * HID + j];
        h3[j] = tanhf(s);
    }
    float o = b4[0];
    #pragma unroll
    for (int k = 0; k < HID; ++k) o += h3[k] * w4[k];
    me[r] = 1.0f / (1.0f + expf(-o));
}

// ---------------- Kernel 2: pipelined, 1 block per body ----------------
// integro_j = dt * sum_{d=1..j} kl[d] * I[j-d],  kl[d] = me[T-d], kl[0] = 0
// Per chunk p (64 steps): wave0 runs the serial recurrence (Phase B) while
// waves 1-3 compute the history part of next chunk's H into registers; then
// all 4 waves add the 64-term tail (chunk p's fresh I values) and write Hs.
__global__ __launch_bounds__(256, 2) void ode_kernel(
    const float* __restrict__ t,
    const float* __restrict__ y,
    const float* __restrict__ me,
    const float* __restrict__ betap,
    const float* __restrict__ gammap,
    float* __restrict__ out)
{
    const int b    = blockIdx.x;
    const int tx   = threadIdx.x;
    const int lane = tx & 63;
    const int wv   = tx >> 6;

    __shared__ float kl[T_N];     // kl[d] = me[T-d], kl[0] = 0
    __shared__ float Ih[T_N];     // I history
    __shared__ float Hs[4][64];   // per-wave H partials for the upcoming chunk

    for (int d = tx; d < T_N; d += 256)
        kl[d] = (d == 0) ? 0.0f : me[T_N - d];
    Hs[wv][lane] = 0.0f;

    const float dt  = t[0] - t[1];     // 1/1024, exact
    const float rdt = 1.0f / dt;
    const float bet = betap[0];
    const float gam = gammap[0];

    float S = y[3 * b + 0];
    float I = y[3 * b + 1];
    float R = y[3 * b + 2];

    if (tx == 0) Ih[0] = I;
    if (tx < 3) {
        out[3 * b + tx] = y[3 * b + tx];                        // solution row 0
        out[TB3 + (size_t)1023 * B_N * 3 + 3 * b + tx] = 0.0f;  // diff row 1023
    }
    __syncthreads();

    for (int p = 0; p < 16; ++p) {
        const int Js = p * 64;
        float hm0 = 0.f, hm1 = 0.f, hm2 = 0.f, hm3 = 0.f;   // waves1-3 Hmain accs

        if (wv == 0) {
            // ---------- Phase B_p: 64 serial Euler steps ----------
            const float hw = Hs[0][lane] + Hs[1][lane] + Hs[2][lane] + Hs[3][lane];
            float W = 0.0f;
            float mS = S, mI = I, mR = R;
            const float cS = S, cI = I, cR = R;

            float kv0 = kl[lane];
            float kv1 = kl[(lane - 1 > 0) ? lane - 1 : 0];
            float kv2 = kl[(lane - 2 > 0) ? lane - 2 : 0];
            float kv3 = kl[(lane - 3 > 0) ? lane - 3 : 0];
            int   kidx = lane - 4;

#define STEP(II, KV, UDT)                                                 \
            {                                                             \
                const int ii = (II);                                      \
                const float tot = bcast_lane(hw + W, ii);                 \
                const float integro = tot * dt;                           \
                const float SI = S * I;                                   \
                const float gI = gam * I;                                 \
                const float dS = fmaf(-bet, SI, integro);                 \
                const float dI = fmaf(bet, SI, -gI);                      \
                S = fmaf(dS, (UDT), S);                                   \
                I = fmaf(dI, (UDT), I);                                   \
                R = fmaf(-(dS + dI), (UDT), R);                           \
                if (lane == ii) { mS = S; mI = I; mR = R; }               \
                W = fmaf(KV, I, W);                                       \
                KV = kl[(kidx > 0) ? kidx : 0];                           \
                --kidx;                                                   \
            }

            {   // first round: step 0 of chunk 0 is the initial condition
                const float dt0 = (p == 0) ? 0.0f : dt;
                STEP(0, kv0, dt0)
                STEP(1, kv1, dt)
                STEP(2, kv2, dt)
                STEP(3, kv3, dt)
            }
            #pragma unroll 1
            for (int q = 1; q < 16; ++q) {
                const int base = q * 4;
                STEP(base + 0, kv0, dt)
                STEP(base + 1, kv1, dt)
                STEP(base + 2, kv2, dt)
                STEP(base + 3, kv3, dt)
            }
#undef STEP

            Ih[Js + lane] = mI;   // publish chunk p history

            // outputs: solution row j; diff row j-1 = (y_j - y_{j-1})/dt
            const int j = Js + lane;
            float pS = __shfl_up(mS, 1);
            float pI = __shfl_up(mI, 1);
            float pR = __shfl_up(mR, 1);
            if (lane == 0) { pS = cS; pI = cI; pR = cR; }
            if (j >= 1) {
                float* so = out + (size_t)j * (B_N * 3) + 3 * b;
                so[0] = mS; so[1] = mI; so[2] = mR;
                float* df = out + TB3 + (size_t)(j - 1) * (B_N * 3) + 3 * b;
                df[0] = (mS - pS) * rdt;
                df[1] = (mI - pI) * rdt;
                df[2] = (mR - pR) * rdt;
            }
        } else if (p < 15) {
            // ---------- Hmain_{p+1} (history i < 64p), runs under B_p ----------
            const int Jt = Js + 64;
            for (int bb = wv - 1; bb < p; bb += 3) {
                const int i0 = bb * 64;
                const float ihv = Ih[i0 + lane];
                const float* kb = &kl[Jt - i0 + lane];
                #pragma unroll
                for (int tq = 0; tq < 64; tq += 4) {
                    hm0 = fmaf(bcast_lane(ihv, tq + 0), kb[-(tq + 0)], hm0);
                    hm1 = fmaf(bcast_lane(ihv, tq + 1), kb[-(tq + 1)], hm1);
                    hm2 = fmaf(bcast_lane(ihv, tq + 2), kb[-(tq + 2)], hm2);
                    hm3 = fmaf(bcast_lane(ihv, tq + 3), kb[-(tq + 3)], hm3);
                }
            }
        }
        __syncthreads();   // barrier A: chunk-p history published, Hmain done

        if (p < 15) {
            // ---------- tail: i in [Js, Js+64), 16 per wave ----------
            const int Jt = Js + 64;
            const int i0 = Js + 16 * wv;
            const float ihv = Ih[i0 + lane];
            const float* kb = &kl[Jt - i0 + lane];
            float t0 = 0.f, t1 = 0.f, t2 = 0.f, t3 = 0.f;
            #pragma unroll
            for (int tq = 0; tq < 16; tq += 4) {
                t0 = fmaf(bcast_lane(ihv, tq + 0), kb[-(tq + 0)], t0);
                t1 = fmaf(bcast_lane(ihv, tq + 1), kb[-(tq + 1)], t1);
                t2 = fmaf(bcast_lane(ihv, tq + 2), kb[-(tq + 2)], t2);
                t3 = fmaf(bcast_lane(ihv, tq + 3), kb[-(tq + 3)], t3);
            }
            const float tacc = (t0 + t1) + (t2 + t3);
            Hs[wv][lane] = (wv == 0) ? tacc
                                     : ((hm0 + hm1) + (hm2 + hm3)) + tacc;
        }
        __syncthreads();   // barrier B: Hs complete for chunk p+1
    }
}

// ---------------- launcher ----------------
extern "C" void kernel_launch(void* const* d_in, const int* in_sizes, int n_in,
                              void* d_out, int out_size, void* d_ws, size_t ws_size,
                              hipStream_t stream)
{
    const float* t   = (const float*)d_in[0];
    const float* y   = (const float*)d_in[1];
    const float* w1  = (const float*)d_in[2];
    const float* b1  = (const float*)d_in[3];
    const float* w2  = (const float*)d_in[4];
    const float* b2  = (const float*)d_in[5];
    const float* w3  = (const float*)d_in[6];
    const float* b3  = (const float*)d_in[7];
    const float* w4  = (const float*)d_in[8];
    const float* b4  = (const float*)d_in[9];
    const float* bet = (const float*)d_in[10];
    const float* gam = (const float*)d_in[11];
    float* out = (float*)d_out;
    float* me  = (float*)d_ws;   // 1024 floats of scratch

    me_mlp_kernel<<<dim3((T_N + 255) / 256), dim3(256), 0, stream>>>(
        t, w1, b1, w2, b2, w3, b3, w4, b4, me);
    ode_kernel<<<dim3(B_N), dim3(256), 0, stream>>>(t, y, me, bet, gam, out);
}

// Round 5
// 145.591 us; speedup vs baseline: 1.8640x; 1.1349x over previous
//
#include <hip/hip_runtime.h>

#define T_N 1024
#define B_N 512
#define HID 20
#define TB3 (T_N * B_N * 3)   // 1572864
#define MEPAD 1152            // me + 128 zero-pad (kl[d<=0] = 0)

typedef float f4v __attribute__((ext_vector_type(4), aligned(4)));

__device__ __forceinline__ float bcast_lane(float v, int l) {
    return __int_as_float(__builtin_amdgcn_readlane(__float_as_int(v), l));
}

// ---------------- Kernel 1: memory MLP (proven round-2 body) + zero pad ----------------
__global__ __launch_bounds__(256) void me_mlp_kernel(
    const float* __restrict__ t,
    const float* __restrict__ w1, const float* __restrict__ b1,
    const float* __restrict__ w2, const float* __restrict__ b2,
    const float* __restrict__ w3, const float* __restrict__ b3,
    const float* __restrict__ w4, const float* __restrict__ b4,
    float* __restrict__ me)
{
    const int r = blockIdx.x * 256 + threadIdx.x;
    if (r >= MEPAD) return;
    if (r >= T_N) { me[r] = 0.0f; return; }   // pad: kl[d<=0] reads land here
    const float x = t[r];
    float h1[HID], h2[HID], h3[HID];
    #pragma unroll
    for (int k = 0; k < HID; ++k) h1[k] = tanhf(x * w1[k] + b1[k]);
    for (int j = 0; j < HID; ++j) {
        float s = b2[j];
        #pragma unroll
        for (int k = 0; k < HID; ++k) s += h1[k] * w2[k * HID + j];
        h2[j] = tanhf(s);
    }
    for (int j = 0; j < HID; ++j) {
        float s = b3[j];
        #pragma unroll
        for (int k = 0; k < HID; ++k) s += h2[k] * w3[k * HID + j];
        h3[j] = tanhf(s);
    }
    float o = b4[0];
    #pragma unroll
    for (int k = 0; k < HID; ++k) o += h3[k] * w4[k];
    me[r] = 1.0f / (1.0f + expf(-o));
}

// ---------------- Kernel 2: pipelined, kl via global/L1 (VMEM pipe) ----------------
// integro_j = dt * sum_{d>=1} kl[d]*I[j-d], kl[d] = me[T-d]; coefficient
// kl[B+lane-tau] == me[T-B-lane+tau] is ASCENDING in tau -> dwordx4-friendly.
__global__ __launch_bounds__(256, 2) void ode_kernel(
    const float* __restrict__ t,
    const float* __restrict__ y,
    const float* __restrict__ me,
    const float* __restrict__ betap,
    const float* __restrict__ gammap,
    float* __restrict__ out)
{
    const int b    = blockIdx.x;
    const int tx   = threadIdx.x;
    const int lane = tx & 63;
    const int wv   = tx >> 6;

    __shared__ float Ih[T_N];     // I history
    __shared__ float Hs[4][64];   // per-wave H partials for the upcoming chunk

    const float dt  = t[0] - t[1];     // 1/1024, exact
    const float rdt = 1.0f / dt;
    const float bet = betap[0];
    const float gam = gammap[0];
    const float Af  = dt * bet;        // I' = fma(Af, S*I, Bf*I)
    const float Bf  = 1.0f - dt * gam;
    const float D2  = dt * dt;         // S' = fma(D2, tot, fma(-Af, S*I, S))

    float S = y[3 * b + 0];
    float I = y[3 * b + 1];
    const float Rc = S + I + y[3 * b + 2];   // S+I+R conserved

    Hs[wv][lane] = 0.0f;
    if (tx == 0) Ih[0] = I;
    if (tx < 3) {
        out[3 * b + tx] = y[3 * b + tx];                        // solution row 0
        out[TB3 + (size_t)1023 * B_N * 3 + 3 * b + tx] = 0.0f;  // diff row 1023
    }
    __syncthreads();

    for (int p = 0; p < 16; ++p) {
        const int Js = p * 64;
        const int Jt = Js + 64;
        float hm0 = 0.f, hm1 = 0.f, hm2 = 0.f, hm3 = 0.f;

        if (wv == 0) {
            // ---------- Phase B_p: 64 serial Euler steps, zero LDS ----------
            float W = Hs[0][lane] + Hs[1][lane] + Hs[2][lane] + Hs[3][lane];
            const float cS = S, cI = I;
            const float A0 = p ? Af : 0.0f;    // chunk-0 step-0 = initial cond
            const float B0 = p ? Bf : 1.0f;
            const float D0 = p ? D2 : 0.0f;

            // lane's W-coefficients: kl[lane-c] = me[T-lane+c], c=0..63
            const float* gk = me + (T_N - lane);
            f4v L[16];
            #pragma unroll
            for (int u = 0; u < 16; ++u) L[u] = *(const f4v*)(gk + 4 * u);

            float mS = S, mI = I;

#define BSTEP(c, Aa, Bb, Dd, KV)                                          \
            {                                                             \
                const float tot = bcast_lane(W, (c));                     \
                const float SI  = S * I;                                  \
                const float tI  = (Bb) * I;                               \
                const float u1  = fmaf(-(Aa), SI, S);                     \
                I = fmaf((Aa), SI, tI);                                   \
                S = fmaf((Dd), tot, u1);                                  \
                if (lane == (c)) { mS = S; mI = I; }                      \
                W = fmaf((KV), I, W);                                     \
            }
#define BGRP(U)                                                           \
            BSTEP(4*(U)+0, Af, Bf, D2, L[U].x)                            \
            BSTEP(4*(U)+1, Af, Bf, D2, L[U].y)                            \
            BSTEP(4*(U)+2, Af, Bf, D2, L[U].z)                            \
            BSTEP(4*(U)+3, Af, Bf, D2, L[U].w)

            BSTEP(0, A0, B0, D0, L[0].x)
            BSTEP(1, Af, Bf, D2, L[0].y)
            BSTEP(2, Af, Bf, D2, L[0].z)
            BSTEP(3, Af, Bf, D2, L[0].w)
            BGRP(1)  BGRP(2)  BGRP(3)  BGRP(4)  BGRP(5)
            BGRP(6)  BGRP(7)  BGRP(8)  BGRP(9)  BGRP(10)
            BGRP(11) BGRP(12) BGRP(13) BGRP(14) BGRP(15)
#undef BGRP
#undef BSTEP

            Ih[Js + lane] = mI;   // publish chunk-p history

            // outputs: solution row j; diff row j-1 = (y_j - y_{j-1})/dt
            const int j = Js + lane;
            float pS = __shfl_up(mS, 1);
            float pI = __shfl_up(mI, 1);
            if (lane == 0) { pS = cS; pI = cI; }
            if (j >= 1) {
                const float mR = Rc - mS - mI;
                float* so = out + (size_t)j * (B_N * 3) + 3 * b;
                so[0] = mS; so[1] = mI; so[2] = mR;
                const float dSo = (mS - pS) * rdt;
                const float dIo = (mI - pI) * rdt;
                float* df = out + TB3 + (size_t)(j - 1) * (B_N * 3) + 3 * b;
                df[0] = dSo; df[1] = dIo; df[2] = -(dSo + dIo);
            }
        } else if (p < 15) {
            // ---------- Hmain_{p+1}: i < 64p, under B_p; kl via global/L1 ----------
            for (int bb = wv - 1; bb < p; bb += 3) {
                const int i0 = bb * 64;
                const float ihv = Ih[i0 + lane];                 // only LDS op
                const float* gk = me + (T_N - (Jt - i0) - lane); // coeff kl[(Jt-i0)+lane-tau]
                f4v L[16];
                #pragma unroll
                for (int u = 0; u < 16; ++u) L[u] = *(const f4v*)(gk + 4 * u);
                #pragma unroll
                for (int u = 0; u < 16; ++u) {
                    hm0 = fmaf(bcast_lane(ihv, 4 * u + 0), L[u].x, hm0);
                    hm1 = fmaf(bcast_lane(ihv, 4 * u + 1), L[u].y, hm1);
                    hm2 = fmaf(bcast_lane(ihv, 4 * u + 2), L[u].z, hm2);
                    hm3 = fmaf(bcast_lane(ihv, 4 * u + 3), L[u].w, hm3);
                }
            }
        }
        __syncthreads();   // chunk-p history published; Hmain done

        if (p < 15) {
            // ---------- tail: i in [Js, Js+64), 16 per wave ----------
            const int i0t = Js + 16 * wv;                        // B_t = 64-16*wv
            const float ihv = Ih[Js + lane];
            const float* gk = me + (T_N - (Jt - i0t) - lane);
            f4v L4[4];
            #pragma unroll
            for (int u = 0; u < 4; ++u) L4[u] = *(const f4v*)(gk + 4 * u);
            float t0 = 0.f, t1 = 0.f, t2 = 0.f, t3 = 0.f;
            #pragma unroll
            for (int u = 0; u < 4; ++u) {
                const int base = 16 * wv + 4 * u;
                t0 = fmaf(bcast_lane(ihv, base + 0), L4[u].x, t0);
                t1 = fmaf(bcast_lane(ihv, base + 1), L4[u].y, t1);
                t2 = fmaf(bcast_lane(ihv, base + 2), L4[u].z, t2);
                t3 = fmaf(bcast_lane(ihv, base + 3), L4[u].w, t3);
            }
            Hs[wv][lane] = ((hm0 + hm1) + (hm2 + hm3)) + ((t0 + t1) + (t2 + t3));
        }
        __syncthreads();   // Hs complete for chunk p+1
    }
}

// ---------------- launcher ----------------
extern "C" void kernel_launch(void* const* d_in, const int* in_sizes, int n_in,
                              void* d_out, int out_size, void* d_ws, size_t ws_size,
                              hipStream_t stream)
{
    const float* t   = (const float*)d_in[0];
    const float* y   = (const float*)d_in[1];
    const float* w1  = (const float*)d_in[2];
    const float* b1  = (const float*)d_in[3];
    const float* w2  = (const float*)d_in[4];
    const float* b2  = (const float*)d_in[5];
    const float* w3  = (const float*)d_in[6];
    const float* b3  = (const float*)d_in[7];
    const float* w4  = (const float*)d_in[8];
    const float* b4  = (const float*)d_in[9];
    const float* bet = (const float*)d_in[10];
    const float* gam = (const float*)d_in[11];
    float* out = (float*)d_out;
    float* me  = (float*)d_ws;   // 1152 floats of scratch (me + zero pad)

    me_mlp_kernel<<<dim3((MEPAD + 255) / 256), dim3(256), 0, stream>>>(
        t, w1, b1, w2, b2, w3, b3, w4, b4, me);
    ode_kernel<<<dim3(B_N), dim3(256), 0, stream>>>(t, y, me, bet, gam, out);
}

// Round 6
// 145.019 us; speedup vs baseline: 1.8714x; 1.0039x over previous
//
#include <hip/hip_runtime.h>

#define T_N 1024
#define B_N 512
#define HID 20
#define TB3 (T_N * B_N * 3)   // 1572864
#define MEPAD 1152            // me + 128 zero-pad (kl[d<=0] = 0)

typedef float f4v __attribute__((ext_vector_type(4), aligned(4)));

__device__ __forceinline__ float bcast_lane(float v, int l) {
    return __int_as_float(__builtin_amdgcn_readlane(__float_as_int(v), l));
}

// ---------------- Kernel 1: memory MLP, LDS-staged weights ----------------
// 18 blocks x 64 threads; thread = row. All weight loads are bounds-checked
// strided loops (no guarded per-lane loads -> no speculated OOB).
__global__ __launch_bounds__(64) void me_mlp_kernel(
    const float* __restrict__ t,
    const float* __restrict__ w1, const float* __restrict__ b1,
    const float* __restrict__ w2, const float* __restrict__ b2,
    const float* __restrict__ w3, const float* __restrict__ b3,
    const float* __restrict__ w4, const float* __restrict__ b4,
    float* __restrict__ me)
{
    __shared__ float sw2[HID * HID], sw3[HID * HID];
    __shared__ float sw1[HID], sb1[HID], sb2[HID], sb3[HID], sw4[HID];
    __shared__ float sb4;
    const int tx = threadIdx.x;

    for (int i = tx; i < HID * HID; i += 64) { sw2[i] = w2[i]; sw3[i] = w3[i]; }
    for (int i = tx; i < HID; i += 64) {
        sw1[i] = w1[i]; sb1[i] = b1[i]; sb2[i] = b2[i];
        sb3[i] = b3[i]; sw4[i] = w4[i];
    }
    if (tx == 0) sb4 = b4[0];
    __syncthreads();

    const int r = blockIdx.x * 64 + tx;
    if (r >= MEPAD) return;
    if (r >= T_N) { me[r] = 0.0f; return; }   // zero pad region

    const float x = t[r];
    float h1[HID], h2[HID], h3[HID];
    #pragma unroll
    for (int k = 0; k < HID; ++k) h1[k] = tanhf(fmaf(x, sw1[k], sb1[k]));
    for (int j = 0; j < HID; ++j) {
        float s = sb2[j];
        #pragma unroll
        for (int k = 0; k < HID; ++k) s = fmaf(h1[k], sw2[k * HID + j], s);
        h2[j] = tanhf(s);
    }
    for (int j = 0; j < HID; ++j) {
        float s = sb3[j];
        #pragma unroll
        for (int k = 0; k < HID; ++k) s = fmaf(h2[k], sw3[k * HID + j], s);
        h3[j] = tanhf(s);
    }
    float o = sb4;
    #pragma unroll
    for (int k = 0; k < HID; ++k) o = fmaf(h3[k], sw4[k], o);
    me[r] = 1.0f / (1.0f + expf(-o));
}

// ---------------- Kernel 2: pipelined; kl via global/L1; batched readlanes ----------------
__global__ __launch_bounds__(256, 2) void ode_kernel(
    const float* __restrict__ t,
    const float* __restrict__ y,
    const float* __restrict__ me,
    const float* __restrict__ betap,
    const float* __restrict__ gammap,
    float* __restrict__ out)
{
    const int b    = blockIdx.x;
    const int tx   = threadIdx.x;
    const int lane = tx & 63;
    const int wv   = tx >> 6;
    const int swv  = b & 3;               // serial wave: spread across SIMDs per block

    __shared__ float Ih[T_N];
    __shared__ float Hs[4][64];

    const float dt  = t[0] - t[1];        // 1/1024, exact
    const float rdt = 1.0f / dt;
    const float bet = betap[0];
    const float gam = gammap[0];
    const float Af  = dt * bet;
    const float Bf  = 1.0f - dt * gam;
    const float D2  = dt * dt;
    const float kl1 = me[T_N - 1];        // kl[1]

    float S = y[3 * b + 0];
    float I = y[3 * b + 1];
    const float Rc = S + I + y[3 * b + 2];

    Hs[wv][lane] = 0.0f;
    if (tx == 0) Ih[0] = I;
    if (tx < 3) {
        out[3 * b + tx] = y[3 * b + tx];
        out[TB3 + (size_t)1023 * B_N * 3 + 3 * b + tx] = 0.0f;
    }
    __syncthreads();

    for (int p = 0; p < 16; ++p) {
        const int Js = p * 64;
        const int Jt = Js + 64;
        float hm0 = 0.f, hm1 = 0.f, hm2 = 0.f, hm3 = 0.f;

        if (wv == swv) {
            // ---------- Phase B_p: 64 serial steps; readlane 1 step off-chain ----------
            float W = Hs[0][lane] + Hs[1][lane] + Hs[2][lane] + Hs[3][lane];
            const float cS = S, cI = I;
            const float A0 = p ? Af : 0.0f;
            const float B0 = p ? Bf : 1.0f;
            const float D0 = p ? D2 : 0.0f;

            const float* gk = me + (T_N - lane);
            f4v L[16];
            #pragma unroll
            for (int u = 0; u < 16; ++u) L[u] = *(const f4v*)(gk + 4 * u);

            float mS = S, mI = I;
            float pre = bcast_lane(W, 0);

            {   // step 0 (chunk 0: initial condition via A0/B0/D0)
                const float tot = pre;
                pre = bcast_lane(W, 1);           // before W update
                const float SI = S * I;
                const float tI = B0 * I;
                const float u1 = fmaf(-A0, SI, S);
                I = fmaf(A0, SI, tI);
                S = fmaf(D0, tot, u1);
                if (lane == 0) { mS = S; mI = I; }
                W = fmaf(L[0].x, I, W);
            }

#define BSTEP(c, KV)                                                      \
            {                                                             \
                const float tot = fmaf(kl1, I, pre);                      \
                pre = bcast_lane(W, ((c) + 1) & 63);                      \
                const float SI = S * I;                                   \
                const float tI = Bf * I;                                  \
                const float u1 = fmaf(-Af, SI, S);                        \
                I = fmaf(Af, SI, tI);                                     \
                S = fmaf(D2, tot, u1);                                    \
                if (lane == (c)) { mS = S; mI = I; }                      \
                W = fmaf((KV), I, W);                                     \
            }
#define BGRP(U)                                                           \
            BSTEP(4*(U)+0, L[U].x)                                        \
            BSTEP(4*(U)+1, L[U].y)                                        \
            BSTEP(4*(U)+2, L[U].z)                                        \
            BSTEP(4*(U)+3, L[U].w)

            BSTEP(1, L[0].y) BSTEP(2, L[0].z) BSTEP(3, L[0].w)
            BGRP(1)  BGRP(2)  BGRP(3)  BGRP(4)  BGRP(5)
            BGRP(6)  BGRP(7)  BGRP(8)  BGRP(9)  BGRP(10)
            BGRP(11) BGRP(12) BGRP(13) BGRP(14) BGRP(15)
#undef BGRP
#undef BSTEP

            Ih[Js + lane] = mI;

            const int j = Js + lane;
            float pS = __shfl_up(mS, 1);
            float pI = __shfl_up(mI, 1);
            if (lane == 0) { pS = cS; pI = cI; }
            if (j >= 1) {
                const float mR = Rc - mS - mI;
                float* so = out + (size_t)j * (B_N * 3) + 3 * b;
                so[0] = mS; so[1] = mI; so[2] = mR;
                const float dSo = (mS - pS) * rdt;
                const float dIo = (mI - pI) * rdt;
                float* df = out + TB3 + (size_t)(j - 1) * (B_N * 3) + 3 * b;
                df[0] = dSo; df[1] = dIo; df[2] = -(dSo + dIo);
            }
        } else if (p < 15) {
            // ---------- Hmain_{p+1}: batched readlanes (groups of 8) ----------
            const int rank = ((wv - swv + 4) & 3) - 1;   // 0..2
            for (int bb = rank; bb < p; bb += 3) {
                const int i0 = bb * 64;
                const float ihv = Ih[i0 + lane];
                const float* gk = me + (T_N - (Jt - i0) - lane);
                f4v L[16];
                #pragma unroll
                for (int u = 0; u < 16; ++u) L[u] = *(const f4v*)(gk + 4 * u);
                #pragma unroll
                for (int g = 0; g < 8; ++g) {
                    const float r0 = bcast_lane(ihv, 8 * g + 0);
                    const float r1 = bcast_lane(ihv, 8 * g + 1);
                    const float r2 = bcast_lane(ihv, 8 * g + 2);
                    const float r3 = bcast_lane(ihv, 8 * g + 3);
                    const float r4 = bcast_lane(ihv, 8 * g + 4);
                    const float r5 = bcast_lane(ihv, 8 * g + 5);
                    const float r6 = bcast_lane(ihv, 8 * g + 6);
                    const float r7 = bcast_lane(ihv, 8 * g + 7);
                    const f4v La = L[2 * g], Lb = L[2 * g + 1];
                    hm0 = fmaf(r0, La.x, hm0);
                    hm1 = fmaf(r1, La.y, hm1);
                    hm2 = fmaf(r2, La.z, hm2);
                    hm3 = fmaf(r3, La.w, hm3);
                    hm0 = fmaf(r4, Lb.x, hm0);
                    hm1 = fmaf(r5, Lb.y, hm1);
                    hm2 = fmaf(r6, Lb.z, hm2);
                    hm3 = fmaf(r7, Lb.w, hm3);
                }
            }
        }
        __syncthreads();

        if (p < 15) {
            // ---------- tail: i in [Js, Js+64), 16 per wave ----------
            const int i0t = Js + 16 * wv;
            const float ihv = Ih[Js + lane];
            const float* gk = me + (T_N - (Jt - i0t) - lane);
            f4v L4[4];
            #pragma unroll
            for (int u = 0; u < 4; ++u) L4[u] = *(const f4v*)(gk + 4 * u);
            float t0 = 0.f, t1 = 0.f, t2 = 0.f, t3 = 0.f;
            #pragma unroll
            for (int g = 0; g < 2; ++g) {
                const int base = 16 * wv + 8 * g;
                const float r0 = bcast_lane(ihv, base + 0);
                const float r1 = bcast_lane(ihv, base + 1);
                const float r2 = bcast_lane(ihv, base + 2);
                const float r3 = bcast_lane(ihv, base + 3);
                const float r4 = bcast_lane(ihv, base + 4);
                const float r5 = bcast_lane(ihv, base + 5);
                const float r6 = bcast_lane(ihv, base + 6);
                const float r7 = bcast_lane(ihv, base + 7);
                const f4v La = L4[2 * g], Lb = L4[2 * g + 1];
                t0 = fmaf(r0, La.x, t0);
                t1 = fmaf(r1, La.y, t1);
                t2 = fmaf(r2, La.z, t2);
                t3 = fmaf(r3, La.w, t3);
                t0 = fmaf(r4, Lb.x, t0);
                t1 = fmaf(r5, Lb.y, t1);
                t2 = fmaf(r6, Lb.z, t2);
                t3 = fmaf(r7, Lb.w, t3);
            }
            const float tacc = ((t0 + t1) + (t2 + t3));
            Hs[wv][lane] = (wv == swv) ? tacc
                                       : ((hm0 + hm1) + (hm2 + hm3)) + tacc;
        }
        __syncthreads();
    }
}

// ---------------- launcher ----------------
extern "C" void kernel_launch(void* const* d_in, const int* in_sizes, int n_in,
                              void* d_out, int out_size, void* d_ws, size_t ws_size,
                              hipStream_t stream)
{
    const float* t   = (const float*)d_in[0];
    const float* y   = (const float*)d_in[1];
    const float* w1  = (const float*)d_in[2];
    const float* b1  = (const float*)d_in[3];
    const float* w2  = (const float*)d_in[4];
    const float* b2  = (const float*)d_in[5];
    const float* w3  = (const float*)d_in[6];
    const float* b3  = (const float*)d_in[7];
    const float* w4  = (const float*)d_in[8];
    const float* b4  = (const float*)d_in[9];
    const float* bet = (const float*)d_in[10];
    const float* gam = (const float*)d_in[11];
    float* out = (float*)d_out;
    float* me  = (float*)d_ws;   // 1152 floats of scratch (me + zero pad)

    me_mlp_kernel<<<dim3(MEPAD / 64), dim3(64), 0, stream>>>(
        t, w1, b1, w2, b2, w3, b3, w4, b4, me);
    ode_kernel<<<dim3(B_N), dim3(256), 0, stream>>>(t, y, me, bet, gam, out);
}